// Round 11
// baseline (50.255 us; speedup 1.0000x reference)
//
#include <hip/hip_runtime.h>
#include <hip/hip_bf16.h>
#include <cstdint>

// Problem dims (fixed by reference)
constexpr int B  = 8;
constexpr int LQ = 256;
constexpr int LK = 256;
constexpr int D  = 512;   // Dq == Dk
constexpr int A  = 256;

constexpr float NEG_INF   = -1e15f;               // matches reference -INFINITY
constexpr float LOG2E     = 1.4426950408889634f;
constexpr float TWO_LOG2E = 2.8853900817779268f;  // folded into W at staging

// GEMM tiling — round-8 proven parameters
constexpr int BR = 32;   // rows per block (q/k rows)
constexpr int BC = 64;   // cols per block (a)
constexpr int BK = 64;   // k-chunk
constexpr int XS_STRIDE = 34;
constexpr int WS_STRIDE = 68;

constexpr int QP_ELEMS = B * LQ * A;              // 524288

// ---------------------------------------------------------------------------
// Combined projection GEMM — EXACT round-10 sync skeleton (proven):
// loads at loop top -> barrier -> stage -> barrier -> compute.
// ONLY change vs round 10: the STAGING THREAD MAPS. Old maps put all four
// k-groups in the same LDS banks (stride*16 ≡ 0 mod 32) -> 4-way write
// conflicts on every staging store. New maps spread a wave's 64 lanes over
// all 32 banks (2 lanes/bank = free):
//   X: thread covers row (t&31), k-range (t>>5)*8 .. +7   (2 float4 loads)
//   W: thread covers col (t&63), k-range (t>>6)*16 .. +15 (4 float4 loads)
// Compute, LDS layout, barriers, epilogue byte-identical to round 10.
// Outputs pre-exponentiated: eq[row][a], ek[b][a>>1][k][a&1].
// ---------------------------------------------------------------------------
__global__ __launch_bounds__(256) void proj_gemm(const float* __restrict__ Q,
                                                 const float* __restrict__ Kin,
                                                 const float* __restrict__ W1,
                                                 const float* __restrict__ W2,
                                                 float* __restrict__ qp,
                                                 float* __restrict__ kp) {
    __shared__ float Xs[BK][XS_STRIDE];  // [k][r]  (transposed X tile)
    __shared__ float Ws[BK][WS_STRIDE];  // [k][c]  (transposed W tile, pre-scaled)

    const int t       = threadIdx.x;
    const int tile_c  = blockIdx.x & 3;        // 4 col tiles (A=256 / BC=64)
    const int tile_r  = blockIdx.x >> 2;       // 128 row tiles
    const int rowbase = tile_r * BR;           // 0..4064
    const bool isQ    = rowbase < 2048;

    const float* X = isQ ? (Q   + (size_t)rowbase * D)
                         : (Kin + (size_t)(rowbase - 2048) * D);
    const float* W = (isQ ? W1 : W2) + (size_t)(tile_c * BC) * D;

    // staging maps (bank-conflict-free LDS writes; see header comment)
    const int sx_r  = t & 31;            // row within X tile
    const int sx_kg = (t >> 5) * 8;      // k-group base: 0,8,..,56
    const int sw_c  = t & 63;            // col within W tile
    const int sw_kg = (t >> 6) * 16;     // k-group base: 0,16,32,48

    // compute maps: thread owns 2 rows x 4 cols (unchanged)
    const int cg = t & 15, rg = t >> 4;
    const int c0 = cg * 4, r0 = rg * 2;

    float acc[2][4] = {};

    for (int k0 = 0; k0 < D; k0 += BK) {
        // issue global loads early
        const float* xptr = X + (size_t)sx_r * D + k0 + sx_kg;
        float4 xa = *(const float4*)(xptr);
        float4 xb = *(const float4*)(xptr + 4);
        const float* wptr = W + (size_t)sw_c * D + k0 + sw_kg;
        float4 wv0 = *(const float4*)(wptr);
        float4 wv1 = *(const float4*)(wptr + 4);
        float4 wv2 = *(const float4*)(wptr + 8);
        float4 wv3 = *(const float4*)(wptr + 12);

        __syncthreads();  // previous chunk's compute done before overwrite

        Xs[sx_kg + 0][sx_r] = xa.x;
        Xs[sx_kg + 1][sx_r] = xa.y;
        Xs[sx_kg + 2][sx_r] = xa.z;
        Xs[sx_kg + 3][sx_r] = xa.w;
        Xs[sx_kg + 4][sx_r] = xb.x;
        Xs[sx_kg + 5][sx_r] = xb.y;
        Xs[sx_kg + 6][sx_r] = xb.z;
        Xs[sx_kg + 7][sx_r] = xb.w;

        Ws[sw_kg +  0][sw_c] = wv0.x * TWO_LOG2E;
        Ws[sw_kg +  1][sw_c] = wv0.y * TWO_LOG2E;
        Ws[sw_kg +  2][sw_c] = wv0.z * TWO_LOG2E;
        Ws[sw_kg +  3][sw_c] = wv0.w * TWO_LOG2E;
        Ws[sw_kg +  4][sw_c] = wv1.x * TWO_LOG2E;
        Ws[sw_kg +  5][sw_c] = wv1.y * TWO_LOG2E;
        Ws[sw_kg +  6][sw_c] = wv1.z * TWO_LOG2E;
        Ws[sw_kg +  7][sw_c] = wv1.w * TWO_LOG2E;
        Ws[sw_kg +  8][sw_c] = wv2.x * TWO_LOG2E;
        Ws[sw_kg +  9][sw_c] = wv2.y * TWO_LOG2E;
        Ws[sw_kg + 10][sw_c] = wv2.z * TWO_LOG2E;
        Ws[sw_kg + 11][sw_c] = wv2.w * TWO_LOG2E;
        Ws[sw_kg + 12][sw_c] = wv3.x * TWO_LOG2E;
        Ws[sw_kg + 13][sw_c] = wv3.y * TWO_LOG2E;
        Ws[sw_kg + 14][sw_c] = wv3.z * TWO_LOG2E;
        Ws[sw_kg + 15][sw_c] = wv3.w * TWO_LOG2E;

        __syncthreads();

#pragma unroll 8
        for (int kk = 0; kk < BK; ++kk) {
            float2 xr = *(const float2*)&Xs[kk][r0];
            float4 wr = *(const float4*)&Ws[kk][c0];
            acc[0][0] = fmaf(xr.x, wr.x, acc[0][0]);
            acc[0][1] = fmaf(xr.x, wr.y, acc[0][1]);
            acc[0][2] = fmaf(xr.x, wr.z, acc[0][2]);
            acc[0][3] = fmaf(xr.x, wr.w, acc[0][3]);
            acc[1][0] = fmaf(xr.y, wr.x, acc[1][0]);
            acc[1][1] = fmaf(xr.y, wr.y, acc[1][1]);
            acc[1][2] = fmaf(xr.y, wr.z, acc[1][2]);
            acc[1][3] = fmaf(xr.y, wr.w, acc[1][3]);
        }
    }

    // epilogue: exponentiate (register-private; sync structure untouched)
#pragma unroll
    for (int i = 0; i < 2; ++i)
#pragma unroll
        for (int j = 0; j < 4; ++j)
            acc[i][j] = __builtin_amdgcn_exp2f(acc[i][j]);

    const int cbase = tile_c * BC;
    if (isQ) {
#pragma unroll
        for (int i = 0; i < 2; ++i) {
            float4 v = make_float4(acc[i][0], acc[i][1], acc[i][2], acc[i][3]);
            *(float4*)(qp + (size_t)(rowbase + r0 + i) * A + cbase + c0) = v;
        }
    } else {
        // transpose 32x64 tile through LDS, then scatter to the
        // a-pair-interleaved layout kp[b][a>>1][k][a&1]
        __syncthreads();
        float* T = &Xs[0][0];  // 64*34 floats, exactly Xs capacity
#pragma unroll
        for (int i = 0; i < 2; ++i)
#pragma unroll
            for (int j = 0; j < 4; ++j)
                T[(c0 + j) * XS_STRIDE + (r0 + i)] = acc[i][j];
        __syncthreads();

        const int bb    = (rowbase - 2048) >> 8;
        const int kbase = rowbase & 255;          // multiple of 32
        const int kk    = t & 31;                 // k within tile
        const int ag    = t >> 5;                 // 0..7
        float* dstb = kp + (size_t)bb * A * LK;
#pragma unroll
        for (int j = 0; j < 8; ++j) {
            int a2 = ag + 8 * j;                  // 0..63
            int a  = cbase + a2;
            dstb[((size_t)(a >> 1) * LK + kbase + kk) * 2 + (a & 1)] =
                T[a2 * XS_STRIDE + kk];
        }
    }
}

// ---------------------------------------------------------------------------
// Fused score + mask + softmax — round-9/10 proven structure extended to
// FOUR q-rows per block (halves ek traffic, 4 independent rcp chains).
// Softmax reduction is the proven 3-barrier pattern, cloned per row.
// score'[q][k] = -2 * sum_a w3[a] / (1 + eq[q][a]*ek[a][k])
// (row-constant sum(w3) dropped: softmax-invariant)
// ---------------------------------------------------------------------------
__global__ __launch_bounds__(256) void score_softmax(const float* __restrict__ qp,
                                                     const float* __restrict__ kpT,
                                                     const int* __restrict__ mask,
                                                     const float* __restrict__ w3,
                                                     float* __restrict__ out) {
    const int t    = threadIdx.x;            // k
    const int row0 = blockIdx.x * 4;         // global q-row
    const int b    = row0 >> 8;

    const float* kpb = kpT + (size_t)b * A * LK;   // [A/2][LK][2] interleaved
    const float* q0  = qp + (size_t)row0 * A;

    float acc0 = 0.f, acc1 = 0.f, acc2 = 0.f, acc3 = 0.f;

#pragma unroll 4
    for (int a = 0; a < A; a += 2) {
        float2 ek = *(const float2*)(kpb + ((size_t)(a >> 1) * LK + t) * 2);
        float w0  = w3[a], w1 = w3[a + 1];             // uniform -> s_load
        float q0a = q0[a],         q0b = q0[a + 1];    // uniform -> s_load
        float q1a = q0[A + a],     q1b = q0[A + a + 1];
        float q2a = q0[2 * A + a], q2b = q0[2 * A + a + 1];
        float q3a = q0[3 * A + a], q3b = q0[3 * A + a + 1];

        // a-column 0
        float f0 = 1.0f + q0a * ek.x;
        float f1 = 1.0f + q1a * ek.x;
        float f2 = 1.0f + q2a * ek.x;
        float f3 = 1.0f + q3a * ek.x;
        float rA = __builtin_amdgcn_rcpf(f0 * f1);
        float rB = __builtin_amdgcn_rcpf(f2 * f3);
        acc0 = fmaf(f1 * rA, w0, acc0);
        acc1 = fmaf(f0 * rA, w0, acc1);
        acc2 = fmaf(f3 * rB, w0, acc2);
        acc3 = fmaf(f2 * rB, w0, acc3);

        // a-column 1
        float g0 = 1.0f + q0b * ek.y;
        float g1 = 1.0f + q1b * ek.y;
        float g2 = 1.0f + q2b * ek.y;
        float g3 = 1.0f + q3b * ek.y;
        float rC = __builtin_amdgcn_rcpf(g0 * g1);
        float rD = __builtin_amdgcn_rcpf(g2 * g3);
        acc0 = fmaf(g1 * rC, w1, acc0);
        acc1 = fmaf(g0 * rC, w1, acc1);
        acc2 = fmaf(g3 * rD, w1, acc2);
        acc3 = fmaf(g2 * rD, w1, acc3);
    }

    // mask + the -2 scale (applied once, preserves softmax ordering)
    const int* mrow = mask + (size_t)row0 * LK;
    float sc0 = (mrow[t]          == 0) ? NEG_INF : -2.0f * acc0;
    float sc1 = (mrow[LK + t]     == 0) ? NEG_INF : -2.0f * acc1;
    float sc2 = (mrow[2 * LK + t] == 0) ? NEG_INF : -2.0f * acc2;
    float sc3 = (mrow[3 * LK + t] == 0) ? NEG_INF : -2.0f * acc3;

    // block softmax over 256 threads (4 waves), 4 rows — proven 3-barrier form
    __shared__ float red[4][8];
    const int wave = t >> 6, lane = t & 63;

    float m0 = sc0, m1 = sc1, m2 = sc2, m3 = sc3;
#pragma unroll
    for (int off = 32; off > 0; off >>= 1) {
        m0 = fmaxf(m0, __shfl_xor(m0, off));
        m1 = fmaxf(m1, __shfl_xor(m1, off));
        m2 = fmaxf(m2, __shfl_xor(m2, off));
        m3 = fmaxf(m3, __shfl_xor(m3, off));
    }
    if (lane == 0) {
        red[0][wave] = m0; red[1][wave] = m1;
        red[2][wave] = m2; red[3][wave] = m3;
    }
    __syncthreads();
    float rmax0 = fmaxf(fmaxf(red[0][0], red[0][1]), fmaxf(red[0][2], red[0][3]));
    float rmax1 = fmaxf(fmaxf(red[1][0], red[1][1]), fmaxf(red[1][2], red[1][3]));
    float rmax2 = fmaxf(fmaxf(red[2][0], red[2][1]), fmaxf(red[2][2], red[2][3]));
    float rmax3 = fmaxf(fmaxf(red[3][0], red[3][1]), fmaxf(red[3][2], red[3][3]));
    __syncthreads();

    float p0 = __builtin_amdgcn_exp2f((sc0 - rmax0) * LOG2E);
    float p1 = __builtin_amdgcn_exp2f((sc1 - rmax1) * LOG2E);
    float p2 = __builtin_amdgcn_exp2f((sc2 - rmax2) * LOG2E);
    float p3 = __builtin_amdgcn_exp2f((sc3 - rmax3) * LOG2E);

    float s0 = p0, s1 = p1, s2 = p2, s3 = p3;
#pragma unroll
    for (int off = 32; off > 0; off >>= 1) {
        s0 += __shfl_xor(s0, off);
        s1 += __shfl_xor(s1, off);
        s2 += __shfl_xor(s2, off);
        s3 += __shfl_xor(s3, off);
    }
    if (lane == 0) {
        red[0][wave] = s0; red[1][wave] = s1;
        red[2][wave] = s2; red[3][wave] = s3;
    }
    __syncthreads();
    float sum0 = (red[0][0] + red[0][1]) + (red[0][2] + red[0][3]);
    float sum1 = (red[1][0] + red[1][1]) + (red[1][2] + red[1][3]);
    float sum2 = (red[2][0] + red[2][1]) + (red[2][2] + red[2][3]);
    float sum3 = (red[3][0] + red[3][1]) + (red[3][2] + red[3][3]);

    out[(size_t)row0 * LK + t]       = p0 * __builtin_amdgcn_rcpf(sum0);
    out[(size_t)(row0 + 1) * LK + t] = p1 * __builtin_amdgcn_rcpf(sum1);
    out[(size_t)(row0 + 2) * LK + t] = p2 * __builtin_amdgcn_rcpf(sum2);
    out[(size_t)(row0 + 3) * LK + t] = p3 * __builtin_amdgcn_rcpf(sum3);
}

extern "C" void kernel_launch(void* const* d_in, const int* in_sizes, int n_in,
                              void* d_out, int out_size, void* d_ws, size_t ws_size,
                              hipStream_t stream) {
    const float* Q    = (const float*)d_in[0];   // [B,LQ,1,D]
    const float* K    = (const float*)d_in[1];   // [B,1,LK,D]
    const int*   mask = (const int*)d_in[2];     // [B,LQ,LK]
    const float* W1   = (const float*)d_in[3];   // [A,D]
    const float* W2   = (const float*)d_in[4];   // [A,D]
    const float* w3   = (const float*)d_in[5];   // [A]
    float* out = (float*)d_out;

    float* ws  = (float*)d_ws;
    float* qp  = ws;                     // [B*LQ][A]       eq = 2^(qproj*2log2e)
    float* kpT = ws + QP_ELEMS;          // [B][A/2][LK][2] ek = 2^(kproj*2log2e)

    proj_gemm<<<512, 256, 0, stream>>>(Q, K, W1, W2, qp, kpT);
    score_softmax<<<(B * LQ) / 4, 256, 0, stream>>>(qp, kpT, mask, w3, out);
}

// Round 12
// 42.392 us; speedup vs baseline: 1.1855x; 1.1855x over previous
//
#include <hip/hip_runtime.h>
#include <hip/hip_bf16.h>
#include <cstdint>

// Problem dims (fixed by reference)
constexpr int B  = 8;
constexpr int LQ = 256;
constexpr int LK = 256;
constexpr int D  = 512;   // Dq == Dk
constexpr int A  = 256;

constexpr float NEG_INF   = -1e15f;               // matches reference -INFINITY
constexpr float LOG2E     = 1.4426950408889634f;
constexpr float TWO_LOG2E = 2.8853900817779268f;  // folded into W at staging

constexpr int QP_ELEMS = B * LQ * A;              // 524288

// MFMA proj tiling: block 64x64, K-chunk 64, 4 waves (each 32x32 = 2x2 frags)
constexpr int BM  = 64;
constexpr int BN  = 64;
constexpr int BKC = 64;
constexpr int LDK = 72;   // LDS k-stride in ushorts (pad: 144B rows, 16B-aligned)

typedef short bf16x8 __attribute__((ext_vector_type(8)));  // 8 bf16 (4 VGPRs)
typedef float f32x4  __attribute__((ext_vector_type(4)));  // 4 fp32 acc

__device__ inline ushort bf16_rne(float x) {
    unsigned u = __float_as_uint(x);
    unsigned r = u + 0x7FFFu + ((u >> 16) & 1u);   // round-to-nearest-even
    return (ushort)(r >> 16);
}
__device__ inline float bf16_f(ushort h) {
    return __uint_as_float(((unsigned)h) << 16);
}

// convert 4 scaled floats -> hi/lo bf16 quads, store as 8B writes
__device__ inline void stage4(ushort* dh, ushort* dl, float4 v, float s) {
    ushort4 h, l;
    float x;
    x = v.x * s; h.x = bf16_rne(x); l.x = bf16_rne(x - bf16_f(h.x));
    x = v.y * s; h.y = bf16_rne(x); l.y = bf16_rne(x - bf16_f(h.y));
    x = v.z * s; h.z = bf16_rne(x); l.z = bf16_rne(x - bf16_f(h.z));
    x = v.w * s; h.w = bf16_rne(x); l.w = bf16_rne(x - bf16_f(h.w));
    *(ushort4*)dh = h;
    *(ushort4*)dl = l;
}

// ---------------------------------------------------------------------------
// Projection GEMM on the matrix cores, split-bf16 (hi+lo), fp32 accumulate:
//   out[row][a] = 2^( (X[row] . W[a]) * 2log2e )
// Ah*Bh + Ah*Bl + Al*Bh (lo*lo dropped, ~2^-16 rel). Operands staged [m][k]
// row-major (native layout — no transposes), converted during staging.
// Sync = proven 2-barrier skeleton: load -> barrier -> stage -> barrier -> MFMA.
// A-frag: row=lane&15, k-slots=(lane>>4)*8.. ; B-frag: col=lane&15, same k
// packing (any within-instruction k-permutation cancels when A,B match).
// C/D: col=lane&15, row=(lane>>4)*4+reg  [m89-verified].
// ---------------------------------------------------------------------------
__global__ __launch_bounds__(256) void proj_gemm(const float* __restrict__ Q,
                                                 const float* __restrict__ Kin,
                                                 const float* __restrict__ W1,
                                                 const float* __restrict__ W2,
                                                 float* __restrict__ qp,
                                                 float* __restrict__ kp) {
    __shared__ ushort LDSB[4][BM][LDK];   // AH, AL, BH, BL (36864 B)
    auto* AH = LDSB[0];
    auto* AL = LDSB[1];
    auto* BH = LDSB[2];
    auto* BL = LDSB[3];

    const int t    = threadIdx.x;
    const int lane = t & 63;
    const int wave = t >> 6;
    const int wm   = (wave >> 1) * 32;    // wave M offset (0/32)
    const int wn   = (wave & 1) * 32;     // wave N offset (0/32)
    const int l15  = lane & 15;
    const int lg   = lane >> 4;           // 0..3

    const int tile_n  = blockIdx.x & 3;   // 4 col tiles (A=256/BN)
    const int tile_m  = blockIdx.x >> 2;  // 64 row tiles (4096/BM)
    const int rowbase = tile_m * BM;
    const int cbase   = tile_n * BN;
    const bool isQ    = rowbase < 2048;

    const float* X  = isQ ? (Q + (size_t)rowbase * D)
                          : (Kin + (size_t)(rowbase - 2048) * D);
    const float* Wp = (isQ ? W1 : W2) + (size_t)cbase * D;

    // staging map: thread covers row sm, 16 k's at sk (4 float4 loads each side)
    const int sm = t >> 2;                // 0..63
    const int sk = (t & 3) * 16;          // 0,16,32,48

    const float* xrow = X + (size_t)sm * D + sk;
    const float* wrow = Wp + (size_t)sm * D + sk;

    f32x4 acc[2][2] = {{{0.f, 0.f, 0.f, 0.f}, {0.f, 0.f, 0.f, 0.f}},
                       {{0.f, 0.f, 0.f, 0.f}, {0.f, 0.f, 0.f, 0.f}}};

    for (int k0 = 0; k0 < D; k0 += BKC) {
        // issue global loads early (fp32)
        float4 xv0 = *(const float4*)(xrow + k0);
        float4 xv1 = *(const float4*)(xrow + k0 + 4);
        float4 xv2 = *(const float4*)(xrow + k0 + 8);
        float4 xv3 = *(const float4*)(xrow + k0 + 12);
        float4 wv0 = *(const float4*)(wrow + k0);
        float4 wv1 = *(const float4*)(wrow + k0 + 4);
        float4 wv2 = *(const float4*)(wrow + k0 + 8);
        float4 wv3 = *(const float4*)(wrow + k0 + 12);

        __syncthreads();  // barrier 1: previous chunk's frag reads done

        stage4(&AH[sm][sk +  0], &AL[sm][sk +  0], xv0, 1.0f);
        stage4(&AH[sm][sk +  4], &AL[sm][sk +  4], xv1, 1.0f);
        stage4(&AH[sm][sk +  8], &AL[sm][sk +  8], xv2, 1.0f);
        stage4(&AH[sm][sk + 12], &AL[sm][sk + 12], xv3, 1.0f);
        stage4(&BH[sm][sk +  0], &BL[sm][sk +  0], wv0, TWO_LOG2E);
        stage4(&BH[sm][sk +  4], &BL[sm][sk +  4], wv1, TWO_LOG2E);
        stage4(&BH[sm][sk +  8], &BL[sm][sk +  8], wv2, TWO_LOG2E);
        stage4(&BH[sm][sk + 12], &BL[sm][sk + 12], wv3, TWO_LOG2E);

        __syncthreads();  // barrier 2: staged tile visible

#pragma unroll
        for (int ks = 0; ks < BKC; ks += 32) {
            const int kf = ks + lg * 8;
            bf16x8 ah0 = *(const bf16x8*)&AH[wm + l15][kf];
            bf16x8 ah1 = *(const bf16x8*)&AH[wm + 16 + l15][kf];
            bf16x8 al0 = *(const bf16x8*)&AL[wm + l15][kf];
            bf16x8 al1 = *(const bf16x8*)&AL[wm + 16 + l15][kf];
            bf16x8 bh0 = *(const bf16x8*)&BH[wn + l15][kf];
            bf16x8 bh1 = *(const bf16x8*)&BH[wn + 16 + l15][kf];
            bf16x8 bl0 = *(const bf16x8*)&BL[wn + l15][kf];
            bf16x8 bl1 = *(const bf16x8*)&BL[wn + 16 + l15][kf];

            acc[0][0] = __builtin_amdgcn_mfma_f32_16x16x32_bf16(ah0, bh0, acc[0][0], 0, 0, 0);
            acc[0][1] = __builtin_amdgcn_mfma_f32_16x16x32_bf16(ah0, bh1, acc[0][1], 0, 0, 0);
            acc[1][0] = __builtin_amdgcn_mfma_f32_16x16x32_bf16(ah1, bh0, acc[1][0], 0, 0, 0);
            acc[1][1] = __builtin_amdgcn_mfma_f32_16x16x32_bf16(ah1, bh1, acc[1][1], 0, 0, 0);

            acc[0][0] = __builtin_amdgcn_mfma_f32_16x16x32_bf16(ah0, bl0, acc[0][0], 0, 0, 0);
            acc[0][1] = __builtin_amdgcn_mfma_f32_16x16x32_bf16(ah0, bl1, acc[0][1], 0, 0, 0);
            acc[1][0] = __builtin_amdgcn_mfma_f32_16x16x32_bf16(ah1, bl0, acc[1][0], 0, 0, 0);
            acc[1][1] = __builtin_amdgcn_mfma_f32_16x16x32_bf16(ah1, bl1, acc[1][1], 0, 0, 0);

            acc[0][0] = __builtin_amdgcn_mfma_f32_16x16x32_bf16(al0, bh0, acc[0][0], 0, 0, 0);
            acc[0][1] = __builtin_amdgcn_mfma_f32_16x16x32_bf16(al0, bh1, acc[0][1], 0, 0, 0);
            acc[1][0] = __builtin_amdgcn_mfma_f32_16x16x32_bf16(al1, bh0, acc[1][0], 0, 0, 0);
            acc[1][1] = __builtin_amdgcn_mfma_f32_16x16x32_bf16(al1, bh1, acc[1][1], 0, 0, 0);
        }
    }

    // epilogue: exponentiate (register-private)
    float ex[2][2][4];
#pragma unroll
    for (int mi = 0; mi < 2; ++mi)
#pragma unroll
        for (int ni = 0; ni < 2; ++ni)
#pragma unroll
            for (int r = 0; r < 4; ++r)
                ex[mi][ni][r] = __builtin_amdgcn_exp2f(acc[mi][ni][r]);

    if (isQ) {
        // direct store: lanes 0-15 write consecutive a (64B segments)
#pragma unroll
        for (int mi = 0; mi < 2; ++mi)
#pragma unroll
            for (int ni = 0; ni < 2; ++ni)
#pragma unroll
                for (int r = 0; r < 4; ++r) {
                    int row = rowbase + wm + mi * 16 + lg * 4 + r;
                    int col = cbase + wn + ni * 16 + l15;
                    qp[(size_t)row * A + col] = ex[mi][ni][r];
                }
    } else {
        // proven pattern: barrier -> LDS transpose -> barrier -> coalesced scatter
        __syncthreads();   // all frag reads of LDSB done
        float* T = (float*)&LDSB[0][0][0];  // 64x65 f32 = 16640 B <= 36864 B
#pragma unroll
        for (int mi = 0; mi < 2; ++mi)
#pragma unroll
            for (int ni = 0; ni < 2; ++ni)
#pragma unroll
                for (int r = 0; r < 4; ++r) {
                    int m = wm + mi * 16 + lg * 4 + r;   // k-row within tile
                    int n = wn + ni * 16 + l15;          // a-col within tile
                    T[m * 65 + n] = ex[mi][ni][r];
                }
        __syncthreads();

        const int bb    = (rowbase - 2048) >> 8;
        const int kbase = rowbase & 255;
        float* dstb = kp + (size_t)bb * A * LK;
        // a-pair-interleaved layout kp[b][a>>1][k][a&1]; fully coalesced writes
#pragma unroll
        for (int j = 0; j < 16; ++j) {
            int g  = j * 256 + t;        // 0..4095 over the 64x64 tile
            int ii = g & 1;              // a&1
            int kk = (g >> 1) & 63;      // k within tile
            int p  = g >> 7;             // a-pair within tile (0..31)
            dstb[((size_t)(cbase / 2 + p) * LK + kbase + kk) * 2 + ii] =
                T[kk * 65 + 2 * p + ii];
        }
    }
}

// ---------------------------------------------------------------------------
// Fused score + mask + softmax — EXACT round-11 kernel (post-timing proven):
// 4 q-rows/block, float2 interleaved ek, 4 independent shared-rcp chains.
// score'[q][k] = -2 * sum_a w3[a] / (1 + eq[q][a]*ek[a][k])
// (row-constant sum(w3) dropped: softmax-invariant)
// ---------------------------------------------------------------------------
__global__ __launch_bounds__(256) void score_softmax(const float* __restrict__ qp,
                                                     const float* __restrict__ kpT,
                                                     const int* __restrict__ mask,
                                                     const float* __restrict__ w3,
                                                     float* __restrict__ out) {
    const int t    = threadIdx.x;            // k
    const int row0 = blockIdx.x * 4;         // global q-row
    const int b    = row0 >> 8;

    const float* kpb = kpT + (size_t)b * A * LK;   // [A/2][LK][2] interleaved
    const float* q0  = qp + (size_t)row0 * A;

    float acc0 = 0.f, acc1 = 0.f, acc2 = 0.f, acc3 = 0.f;

#pragma unroll 4
    for (int a = 0; a < A; a += 2) {
        float2 ek = *(const float2*)(kpb + ((size_t)(a >> 1) * LK + t) * 2);
        float w0  = w3[a], w1 = w3[a + 1];             // uniform -> s_load
        float q0a = q0[a],         q0b = q0[a + 1];    // uniform -> s_load
        float q1a = q0[A + a],     q1b = q0[A + a + 1];
        float q2a = q0[2 * A + a], q2b = q0[2 * A + a + 1];
        float q3a = q0[3 * A + a], q3b = q0[3 * A + a + 1];

        float f0 = 1.0f + q0a * ek.x;
        float f1 = 1.0f + q1a * ek.x;
        float f2 = 1.0f + q2a * ek.x;
        float f3 = 1.0f + q3a * ek.x;
        float rA = __builtin_amdgcn_rcpf(f0 * f1);
        float rB = __builtin_amdgcn_rcpf(f2 * f3);
        acc0 = fmaf(f1 * rA, w0, acc0);
        acc1 = fmaf(f0 * rA, w0, acc1);
        acc2 = fmaf(f3 * rB, w0, acc2);
        acc3 = fmaf(f2 * rB, w0, acc3);

        float g0 = 1.0f + q0b * ek.y;
        float g1 = 1.0f + q1b * ek.y;
        float g2 = 1.0f + q2b * ek.y;
        float g3 = 1.0f + q3b * ek.y;
        float rC = __builtin_amdgcn_rcpf(g0 * g1);
        float rD = __builtin_amdgcn_rcpf(g2 * g3);
        acc0 = fmaf(g1 * rC, w1, acc0);
        acc1 = fmaf(g0 * rC, w1, acc1);
        acc2 = fmaf(g3 * rD, w1, acc2);
        acc3 = fmaf(g2 * rD, w1, acc3);
    }

    // mask + the -2 scale (applied once, preserves softmax ordering)
    const int* mrow = mask + (size_t)row0 * LK;
    float sc0 = (mrow[t]          == 0) ? NEG_INF : -2.0f * acc0;
    float sc1 = (mrow[LK + t]     == 0) ? NEG_INF : -2.0f * acc1;
    float sc2 = (mrow[2 * LK + t] == 0) ? NEG_INF : -2.0f * acc2;
    float sc3 = (mrow[3 * LK + t] == 0) ? NEG_INF : -2.0f * acc3;

    // block softmax over 256 threads (4 waves), 4 rows — proven 3-barrier form
    __shared__ float red[4][8];
    const int wave = t >> 6, lane = t & 63;

    float m0 = sc0, m1 = sc1, m2 = sc2, m3 = sc3;
#pragma unroll
    for (int off = 32; off > 0; off >>= 1) {
        m0 = fmaxf(m0, __shfl_xor(m0, off));
        m1 = fmaxf(m1, __shfl_xor(m1, off));
        m2 = fmaxf(m2, __shfl_xor(m2, off));
        m3 = fmaxf(m3, __shfl_xor(m3, off));
    }
    if (lane == 0) {
        red[0][wave] = m0; red[1][wave] = m1;
        red[2][wave] = m2; red[3][wave] = m3;
    }
    __syncthreads();
    float rmax0 = fmaxf(fmaxf(red[0][0], red[0][1]), fmaxf(red[0][2], red[0][3]));
    float rmax1 = fmaxf(fmaxf(red[1][0], red[1][1]), fmaxf(red[1][2], red[1][3]));
    float rmax2 = fmaxf(fmaxf(red[2][0], red[2][1]), fmaxf(red[2][2], red[2][3]));
    float rmax3 = fmaxf(fmaxf(red[3][0], red[3][1]), fmaxf(red[3][2], red[3][3]));
    __syncthreads();

    float p0 = __builtin_amdgcn_exp2f((sc0 - rmax0) * LOG2E);
    float p1 = __builtin_amdgcn_exp2f((sc1 - rmax1) * LOG2E);
    float p2 = __builtin_amdgcn_exp2f((sc2 - rmax2) * LOG2E);
    float p3 = __builtin_amdgcn_exp2f((sc3 - rmax3) * LOG2E);

    float s0 = p0, s1 = p1, s2 = p2, s3 = p3;
#pragma unroll
    for (int off = 32; off > 0; off >>= 1) {
        s0 += __shfl_xor(s0, off);
        s1 += __shfl_xor(s1, off);
        s2 += __shfl_xor(s2, off);
        s3 += __shfl_xor(s3, off);
    }
    if (lane == 0) {
        red[0][wave] = s0; red[1][wave] = s1;
        red[2][wave] = s2; red[3][wave] = s3;
    }
    __syncthreads();
    float sum0 = (red[0][0] + red[0][1]) + (red[0][2] + red[0][3]);
    float sum1 = (red[1][0] + red[1][1]) + (red[1][2] + red[1][3]);
    float sum2 = (red[2][0] + red[2][1]) + (red[2][2] + red[2][3]);
    float sum3 = (red[3][0] + red[3][1]) + (red[3][2] + red[3][3]);

    out[(size_t)row0 * LK + t]       = p0 * __builtin_amdgcn_rcpf(sum0);
    out[(size_t)(row0 + 1) * LK + t] = p1 * __builtin_amdgcn_rcpf(sum1);
    out[(size_t)(row0 + 2) * LK + t] = p2 * __builtin_amdgcn_rcpf(sum2);
    out[(size_t)(row0 + 3) * LK + t] = p3 * __builtin_amdgcn_rcpf(sum3);
}

extern "C" void kernel_launch(void* const* d_in, const int* in_sizes, int n_in,
                              void* d_out, int out_size, void* d_ws, size_t ws_size,
                              hipStream_t stream) {
    const float* Q    = (const float*)d_in[0];   // [B,LQ,1,D]
    const float* K    = (const float*)d_in[1];   // [B,1,LK,D]
    const int*   mask = (const int*)d_in[2];     // [B,LQ,LK]
    const float* W1   = (const float*)d_in[3];   // [A,D]
    const float* W2   = (const float*)d_in[4];   // [A,D]
    const float* w3   = (const float*)d_in[5];   // [A]
    float* out = (float*)d_out;

    float* ws  = (float*)d_ws;
    float* qp  = ws;                     // [B*LQ][A]       eq = 2^(qproj*2log2e)
    float* kpT = ws + QP_ELEMS;          // [B][A/2][LK][2] ek = 2^(kproj*2log2e)

    proj_gemm<<<256, 256, 0, stream>>>(Q, K, W1, W2, qp, kpT);
    score_softmax<<<(B * LQ) / 4, 256, 0, stream>>>(qp, kpT, mask, w3, out);
}

// Round 13
// 38.985 us; speedup vs baseline: 1.2891x; 1.0874x over previous
//
#include <hip/hip_runtime.h>
#include <hip/hip_bf16.h>
#include <cstdint>

// Problem dims (fixed by reference)
constexpr int B  = 8;
constexpr int LQ = 256;
constexpr int LK = 256;
constexpr int D  = 512;   // Dq == Dk
constexpr int A  = 256;

constexpr float NEG_INF   = -1e15f;               // matches reference -INFINITY
constexpr float LOG2E     = 1.4426950408889634f;
constexpr float TWO_LOG2E = 2.8853900817779268f;  // applied in proj epilogue

constexpr int QP_ELEMS = B * LQ * A;              // 524288

// MFMA proj tiling: block 64x32, K-chunk 64, 4 waves (each 32x16 = 2x1 frags)
constexpr int BM  = 64;
constexpr int BN  = 32;
constexpr int BKC = 64;
constexpr int LDK = 72;   // LDS k-stride in ushorts (144B rows)

typedef short bf16x8 __attribute__((ext_vector_type(8)));  // 8 bf16 (4 VGPRs)
typedef float f32x4  __attribute__((ext_vector_type(4)));  // 4 fp32 acc

// split x into hi (truncated bf16) + lo (truncated bf16 of remainder);
// pack two elements' hi/lo into dwords. ~9 VALU per 2 elements.
__device__ inline void split2(float x0, float x1, unsigned& hi, unsigned& lo) {
    unsigned u0 = __float_as_uint(x0), u1 = __float_as_uint(x1);
    unsigned h0 = u0 & 0xFFFF0000u, h1 = u1 & 0xFFFF0000u;
    hi = h1 | (u0 >> 16);
    float l0 = x0 - __uint_as_float(h0);
    float l1 = x1 - __uint_as_float(h1);
    lo = (__float_as_uint(l1) & 0xFFFF0000u) | (__float_as_uint(l0) >> 16);
}

__device__ inline void cvt8(float4 a, float4 b, uint4& hi, uint4& lo) {
    split2(a.x, a.y, hi.x, lo.x);
    split2(a.z, a.w, hi.y, lo.y);
    split2(b.x, b.y, hi.z, lo.z);
    split2(b.z, b.w, hi.w, lo.w);
}

// ---------------------------------------------------------------------------
// Projection GEMM on matrix cores, split-bf16 (hi+lo), fp32 accumulate.
// Round-12 proven skeleton (2 barriers/chunk, [m][k] row-major staging, same
// frag/k-packing argument, m89 C/D layout). Changes: BN=32 (grid 512 = 2
// blocks/CU), truncate-split staging (no rne chains, no staging muls),
// TWO_LOG2E applied in the exp2 epilogue.
//   qp[row][a] = 2^(acc*2log2e);  kp[b][a>>1][k][a&1] = same for K rows.
// ---------------------------------------------------------------------------
__global__ __launch_bounds__(256) void proj_gemm(const float* __restrict__ Q,
                                                 const float* __restrict__ Kin,
                                                 const float* __restrict__ W1,
                                                 const float* __restrict__ W2,
                                                 float* __restrict__ qp,
                                                 float* __restrict__ kp) {
    __shared__ ushort AH[BM][LDK], AL[BM][LDK];   // 9216 B each
    __shared__ ushort BH[BN][LDK], BL[BN][LDK];   // 4608 B each

    const int t    = threadIdx.x;
    const int lane = t & 63;
    const int wave = t >> 6;
    const int wm   = (wave >> 1) * 32;    // wave M offset (0/32)
    const int wn   = (wave & 1) * 16;     // wave N offset (0/16)
    const int l15  = lane & 15;
    const int lg   = lane >> 4;           // 0..3

    const int tile_n  = blockIdx.x & 7;   // 8 col tiles (A/BN)
    const int tile_m  = blockIdx.x >> 3;  // 64 row tiles (4096/BM)
    const int rowbase = tile_m * BM;
    const int cbase   = tile_n * BN;
    const bool isQ    = rowbase < 2048;

    const float* X  = isQ ? (Q + (size_t)rowbase * D)
                          : (Kin + (size_t)(rowbase - 2048) * D);
    const float* Wp = (isQ ? W1 : W2) + (size_t)cbase * D;

    // staging maps
    const int sxm = t >> 2;               // X row 0..63
    const int sxk = (t & 3) * 16;         // 16 k's (4 float4)
    const int swm = t >> 3;               // W row 0..31
    const int swk = (t & 7) * 8;          // 8 k's (2 float4)

    const float* xrow = X + (size_t)sxm * D + sxk;
    const float* wrow = Wp + (size_t)swm * D + swk;

    f32x4 acc[2] = {{0.f, 0.f, 0.f, 0.f}, {0.f, 0.f, 0.f, 0.f}};

    for (int k0 = 0; k0 < D; k0 += BKC) {
        // issue global loads early (fp32)
        float4 xv0 = *(const float4*)(xrow + k0);
        float4 xv1 = *(const float4*)(xrow + k0 + 4);
        float4 xv2 = *(const float4*)(xrow + k0 + 8);
        float4 xv3 = *(const float4*)(xrow + k0 + 12);
        float4 wv0 = *(const float4*)(wrow + k0);
        float4 wv1 = *(const float4*)(wrow + k0 + 4);

        __syncthreads();  // barrier 1: previous chunk's frag reads done

        uint4 h0, l0, h1, l1;
        cvt8(xv0, xv1, h0, l0);
        cvt8(xv2, xv3, h1, l1);
        *(uint4*)&AH[sxm][sxk]     = h0;
        *(uint4*)&AH[sxm][sxk + 8] = h1;
        *(uint4*)&AL[sxm][sxk]     = l0;
        *(uint4*)&AL[sxm][sxk + 8] = l1;

        uint4 hw, lw;
        cvt8(wv0, wv1, hw, lw);
        *(uint4*)&BH[swm][swk] = hw;
        *(uint4*)&BL[swm][swk] = lw;

        __syncthreads();  // barrier 2: staged tile visible

#pragma unroll
        for (int ks = 0; ks < BKC; ks += 32) {
            const int kf = ks + lg * 8;
            bf16x8 ah0 = *(const bf16x8*)&AH[wm + l15][kf];
            bf16x8 ah1 = *(const bf16x8*)&AH[wm + 16 + l15][kf];
            bf16x8 al0 = *(const bf16x8*)&AL[wm + l15][kf];
            bf16x8 al1 = *(const bf16x8*)&AL[wm + 16 + l15][kf];
            bf16x8 bh  = *(const bf16x8*)&BH[wn + l15][kf];
            bf16x8 bl  = *(const bf16x8*)&BL[wn + l15][kf];

            acc[0] = __builtin_amdgcn_mfma_f32_16x16x32_bf16(ah0, bh, acc[0], 0, 0, 0);
            acc[1] = __builtin_amdgcn_mfma_f32_16x16x32_bf16(ah1, bh, acc[1], 0, 0, 0);
            acc[0] = __builtin_amdgcn_mfma_f32_16x16x32_bf16(ah0, bl, acc[0], 0, 0, 0);
            acc[1] = __builtin_amdgcn_mfma_f32_16x16x32_bf16(ah1, bl, acc[1], 0, 0, 0);
            acc[0] = __builtin_amdgcn_mfma_f32_16x16x32_bf16(al0, bh, acc[0], 0, 0, 0);
            acc[1] = __builtin_amdgcn_mfma_f32_16x16x32_bf16(al1, bh, acc[1], 0, 0, 0);
        }
    }

    // epilogue: scale + exponentiate (register-private)
    float ex[2][4];
#pragma unroll
    for (int mi = 0; mi < 2; ++mi)
#pragma unroll
        for (int r = 0; r < 4; ++r)
            ex[mi][r] = __builtin_amdgcn_exp2f(acc[mi][r] * TWO_LOG2E);

    if (isQ) {
#pragma unroll
        for (int mi = 0; mi < 2; ++mi)
#pragma unroll
            for (int r = 0; r < 4; ++r) {
                int row = rowbase + wm + mi * 16 + lg * 4 + r;
                int col = cbase + wn + l15;
                qp[(size_t)row * A + col] = ex[mi][r];
            }
    } else {
        // proven pattern: barrier -> LDS transpose -> barrier -> coalesced scatter
        __syncthreads();   // all frag reads of AH/AL done before overwrite
        float* T = (float*)&AH[0][0];  // 64x33 f32 = 8448 B <= 9216 B
#pragma unroll
        for (int mi = 0; mi < 2; ++mi)
#pragma unroll
            for (int r = 0; r < 4; ++r) {
                int m = wm + mi * 16 + lg * 4 + r;   // k-row within tile
                int n = wn + l15;                    // a-col within tile
                T[m * 33 + n] = ex[mi][r];
            }
        __syncthreads();

        const int bb    = (rowbase - 2048) >> 8;
        const int kbase = rowbase & 255;
        float* dstb = kp + (size_t)bb * A * LK;
        // a-pair-interleaved layout kp[b][a>>1][k][a&1]; coalesced writes
#pragma unroll
        for (int j = 0; j < 8; ++j) {
            int g  = j * 256 + t;        // 0..2047 over the 64k x 32a tile
            int ii = g & 1;              // a&1
            int kk = (g >> 1) & 63;      // k within tile
            int p  = g >> 7;             // a-pair within tile (0..15)
            dstb[((size_t)(tile_n * 16 + p) * LK + kbase + kk) * 2 + ii] =
                T[kk * 33 + 2 * p + ii];
        }
    }
}

// ---------------------------------------------------------------------------
// Fused score + mask + softmax — EXACT round-11/12 kernel (post-timing proven
// twice): 4 q-rows/block, float2 interleaved ek, 4 shared-rcp chains.
// score'[q][k] = -2 * sum_a w3[a] / (1 + eq[q][a]*ek[a][k])
// (row-constant sum(w3) dropped: softmax-invariant)
// ---------------------------------------------------------------------------
__global__ __launch_bounds__(256) void score_softmax(const float* __restrict__ qp,
                                                     const float* __restrict__ kpT,
                                                     const int* __restrict__ mask,
                                                     const float* __restrict__ w3,
                                                     float* __restrict__ out) {
    const int t    = threadIdx.x;            // k
    const int row0 = blockIdx.x * 4;         // global q-row
    const int b    = row0 >> 8;

    const float* kpb = kpT + (size_t)b * A * LK;   // [A/2][LK][2] interleaved
    const float* q0  = qp + (size_t)row0 * A;

    float acc0 = 0.f, acc1 = 0.f, acc2 = 0.f, acc3 = 0.f;

#pragma unroll 4
    for (int a = 0; a < A; a += 2) {
        float2 ek = *(const float2*)(kpb + ((size_t)(a >> 1) * LK + t) * 2);
        float w0  = w3[a], w1 = w3[a + 1];             // uniform -> s_load
        float q0a = q0[a],         q0b = q0[a + 1];    // uniform -> s_load
        float q1a = q0[A + a],     q1b = q0[A + a + 1];
        float q2a = q0[2 * A + a], q2b = q0[2 * A + a + 1];
        float q3a = q0[3 * A + a], q3b = q0[3 * A + a + 1];

        float f0 = 1.0f + q0a * ek.x;
        float f1 = 1.0f + q1a * ek.x;
        float f2 = 1.0f + q2a * ek.x;
        float f3 = 1.0f + q3a * ek.x;
        float rA = __builtin_amdgcn_rcpf(f0 * f1);
        float rB = __builtin_amdgcn_rcpf(f2 * f3);
        acc0 = fmaf(f1 * rA, w0, acc0);
        acc1 = fmaf(f0 * rA, w0, acc1);
        acc2 = fmaf(f3 * rB, w0, acc2);
        acc3 = fmaf(f2 * rB, w0, acc3);

        float g0 = 1.0f + q0b * ek.y;
        float g1 = 1.0f + q1b * ek.y;
        float g2 = 1.0f + q2b * ek.y;
        float g3 = 1.0f + q3b * ek.y;
        float rC = __builtin_amdgcn_rcpf(g0 * g1);
        float rD = __builtin_amdgcn_rcpf(g2 * g3);
        acc0 = fmaf(g1 * rC, w1, acc0);
        acc1 = fmaf(g0 * rC, w1, acc1);
        acc2 = fmaf(g3 * rD, w1, acc2);
        acc3 = fmaf(g2 * rD, w1, acc3);
    }

    // mask + the -2 scale (applied once, preserves softmax ordering)
    const int* mrow = mask + (size_t)row0 * LK;
    float sc0 = (mrow[t]          == 0) ? NEG_INF : -2.0f * acc0;
    float sc1 = (mrow[LK + t]     == 0) ? NEG_INF : -2.0f * acc1;
    float sc2 = (mrow[2 * LK + t] == 0) ? NEG_INF : -2.0f * acc2;
    float sc3 = (mrow[3 * LK + t] == 0) ? NEG_INF : -2.0f * acc3;

    // block softmax over 256 threads (4 waves), 4 rows — proven 3-barrier form
    __shared__ float red[4][8];
    const int wave = t >> 6, lane = t & 63;

    float m0 = sc0, m1 = sc1, m2 = sc2, m3 = sc3;
#pragma unroll
    for (int off = 32; off > 0; off >>= 1) {
        m0 = fmaxf(m0, __shfl_xor(m0, off));
        m1 = fmaxf(m1, __shfl_xor(m1, off));
        m2 = fmaxf(m2, __shfl_xor(m2, off));
        m3 = fmaxf(m3, __shfl_xor(m3, off));
    }
    if (lane == 0) {
        red[0][wave] = m0; red[1][wave] = m1;
        red[2][wave] = m2; red[3][wave] = m3;
    }
    __syncthreads();
    float rmax0 = fmaxf(fmaxf(red[0][0], red[0][1]), fmaxf(red[0][2], red[0][3]));
    float rmax1 = fmaxf(fmaxf(red[1][0], red[1][1]), fmaxf(red[1][2], red[1][3]));
    float rmax2 = fmaxf(fmaxf(red[2][0], red[2][1]), fmaxf(red[2][2], red[2][3]));
    float rmax3 = fmaxf(fmaxf(red[3][0], red[3][1]), fmaxf(red[3][2], red[3][3]));
    __syncthreads();

    float p0 = __builtin_amdgcn_exp2f((sc0 - rmax0) * LOG2E);
    float p1 = __builtin_amdgcn_exp2f((sc1 - rmax1) * LOG2E);
    float p2 = __builtin_amdgcn_exp2f((sc2 - rmax2) * LOG2E);
    float p3 = __builtin_amdgcn_exp2f((sc3 - rmax3) * LOG2E);

    float s0 = p0, s1 = p1, s2 = p2, s3 = p3;
#pragma unroll
    for (int off = 32; off > 0; off >>= 1) {
        s0 += __shfl_xor(s0, off);
        s1 += __shfl_xor(s1, off);
        s2 += __shfl_xor(s2, off);
        s3 += __shfl_xor(s3, off);
    }
    if (lane == 0) {
        red[0][wave] = s0; red[1][wave] = s1;
        red[2][wave] = s2; red[3][wave] = s3;
    }
    __syncthreads();
    float sum0 = (red[0][0] + red[0][1]) + (red[0][2] + red[0][3]);
    float sum1 = (red[1][0] + red[1][1]) + (red[1][2] + red[1][3]);
    float sum2 = (red[2][0] + red[2][1]) + (red[2][2] + red[2][3]);
    float sum3 = (red[3][0] + red[3][1]) + (red[3][2] + red[3][3]);

    out[(size_t)row0 * LK + t]       = p0 * __builtin_amdgcn_rcpf(sum0);
    out[(size_t)(row0 + 1) * LK + t] = p1 * __builtin_amdgcn_rcpf(sum1);
    out[(size_t)(row0 + 2) * LK + t] = p2 * __builtin_amdgcn_rcpf(sum2);
    out[(size_t)(row0 + 3) * LK + t] = p3 * __builtin_amdgcn_rcpf(sum3);
}

extern "C" void kernel_launch(void* const* d_in, const int* in_sizes, int n_in,
                              void* d_out, int out_size, void* d_ws, size_t ws_size,
                              hipStream_t stream) {
    const float* Q    = (const float*)d_in[0];   // [B,LQ,1,D]
    const float* K    = (const float*)d_in[1];   // [B,1,LK,D]
    const int*   mask = (const int*)d_in[2];     // [B,LQ,LK]
    const float* W1   = (const float*)d_in[3];   // [A,D]
    const float* W2   = (const float*)d_in[4];   // [A,D]
    const float* w3   = (const float*)d_in[5];   // [A]
    float* out = (float*)d_out;

    float* ws  = (float*)d_ws;
    float* qp  = ws;                     // [B*LQ][A]       eq = 2^(qproj*2log2e)
    float* kpT = ws + QP_ELEMS;          // [B][A/2][LK][2] ek = 2^(kproj*2log2e)

    proj_gemm<<<512, 256, 0, stream>>>(Q, K, W1, W2, qp, kpT);
    score_softmax<<<(B * LQ) / 4, 256, 0, stream>>>(qp, kpT, mask, w3, out);
}